// Round 17
// baseline (503.041 us; speedup 1.0000x reference)
//
#include <hip/hip_runtime.h>
#include <math.h>

#define B_   64
#define T_   500
#define IN_  1024
#define G_   8
#define HG_  128
#define J3_  384   // 3*HG

typedef _Float16 half8 __attribute__((ext_vector_type(8)));
typedef _Float16 half4 __attribute__((ext_vector_type(4)));
typedef float    f32x4 __attribute__((ext_vector_type(4)));

// sigmoid(a) = rcp(1 + exp2(S_RZ*a)); tanh(p) = 2*rcp(1+exp2(S_N*p))-1.
// Scales folded into the f16 weights and bias seeds (no muls in gates).
#define S_RZ (-1.44269504f)
#define S_N  (-2.88539008f)

static __device__ __forceinline__ half8 cvt_half8_s(const float* p, float s) {
    const float4 a = *(const float4*)p;
    const float4 b = *(const float4*)(p + 4);
    half8 h;
    h[0]=(_Float16)(a.x*s); h[1]=(_Float16)(a.y*s); h[2]=(_Float16)(a.z*s); h[3]=(_Float16)(a.w*s);
    h[4]=(_Float16)(b.x*s); h[5]=(_Float16)(b.y*s); h[6]=(_Float16)(b.z*s); h[7]=(_Float16)(b.w*s);
    return h;
}

// opaque reg-to-reg barrier: prevents rematerialization of loop-invariant state
static __device__ __forceinline__ void pin_frag(half8& h) {
    f32x4 t = __builtin_bit_cast(f32x4, h);
    float a = t[0], b = t[1], c = t[2], d = t[3];
    asm volatile("" : "+v"(a), "+v"(b), "+v"(c), "+v"(d));
    t[0] = a; t[1] = b; t[2] = c; t[3] = d;
    h = __builtin_bit_cast(half8, t);
}
static __device__ __forceinline__ void pin_f32x4(f32x4& v) {
    float a = v[0], b = v[1], c = v[2], d = v[3];
    asm volatile("" : "+v"(a), "+v"(b), "+v"(c), "+v"(d));
    v[0] = a; v[1] = b; v[2] = c; v[3] = d;
}

// LDS-only barrier: orders ds ops across the workgroup WITHOUT draining vmcnt.
static __device__ __forceinline__ void barrier_lds_only() {
    asm volatile("s_waitcnt lgkmcnt(0)\n\ts_barrier" ::: "memory");
}

// per-lane select of one element from an f32x4 (constant indices only; the
// two rsel-masks are loop-invariant and hoisted)
static __device__ __forceinline__ float sel4(f32x4 v, int rsel) {
    const float t0 = (rsel & 1) ? v[1] : v[0];
    const float t1 = (rsel & 1) ? v[3] : v[2];
    return (rsel & 2) ? t1 : t0;
}

#define MFMA16(A,Bv,C) __builtin_amdgcn_mfma_f32_16x16x32_f16((A),(Bv),(C),0,0,0)

// ---------------------------------------------------------------------------
// Kernel 0: cast x (fp32) -> x16 (f16), one-shot, memory-bound (~30 us).
// ---------------------------------------------------------------------------
__global__ __launch_bounds__(256)
void cvt_x(const float* __restrict__ x, _Float16* __restrict__ x16)
{
    const size_t n4 = (size_t)B_ * T_ * IN_ / 4;
    const size_t stride = (size_t)gridDim.x * 256;
    for (size_t i = (size_t)blockIdx.x * 256 + threadIdx.x; i < n4; i += stride) {
        const float4 v = ((const float4*)x)[i];
        half4 h;
        h[0] = (_Float16)v.x; h[1] = (_Float16)v.y;
        h[2] = (_Float16)v.z; h[3] = (_Float16)v.w;
        ((half4*)x16)[i] = h;
    }
}

// ---------------------------------------------------------------------------
// Kernel 1 (structure G8 = G7 + 2 blocks/CU):
// 512 blocks x 512 thr (8 waves), ONE real seq/block (b = blk>>3, g = blk&7),
// 16x column duplication on the h-path; x-batch B-cols = 16 TIMESTEPS of the
// one sequence (batch GEMM once per 16 steps, amortized 0.75 MFMA/step).
// amdgpu_waves_per_eu(4,4): exact 4-waves/EU target -> reg cap 128 (current
// use 96) with no incentive to strip further (round-13 disease) -> TWO
// co-resident 8-wave blocks per CU = two independent barrier domains that
// interleave phases and fill the ~690cy/step exposed latency (round-16 PMC).
// Gate dedup: lane owns r = lr&3 (4x dup, 6 trans/wave). xa reads and h
// B-frag reads are fully uniform broadcasts (conflict-free).
// ---------------------------------------------------------------------------
__global__ __launch_bounds__(512) __attribute__((amdgpu_waves_per_eu(4, 4)))
void gru_fused(const float* __restrict__ Wih, const float* __restrict__ Whh,
               const float* __restrict__ bih, const float* __restrict__ bhh,
               const _Float16* __restrict__ x16, float* __restrict__ out)
{
    const int tid  = threadIdx.x;
    const int lane = tid & 63;
    const int w    = tid >> 6;        // wave 0..7 == j-tile
    const int lr   = lane & 15;       // MFMA col: x-path ts, h-path duplicate
    const int hi   = lane >> 4;       // 0..3
    const int blk  = blockIdx.x;      // 0..511
    const int g    = blk & 7;         // == XCD
    const int b    = blk >> 3;        // the ONE real sequence
    const int rsel = lr & 3;          // the ONE r this lane owns
    const int jl   = w * 16 + hi * 4;
    const int jown = jl + rsel;       // owned j

    __shared__ _Float16 h16[2][HG_];         // 512 B: [buf][j]
    __shared__ float    xmem[2][16][392];    // 49 KB: [xbuf][ts][gate*128+j]

    // ---- persistent pinned fragments, gate scales folded in ----
    half8 aI[3][4], aH[3][4];
#pragma unroll
    for (int p = 0; p < 3; ++p)
#pragma unroll
        for (int kt = 0; kt < 4; ++kt) {
            const size_t roff = (size_t)(g * J3_ + p * 128 + w * 16 + lr) * HG_
                              + kt * 32 + hi * 8;
            const float s = (p == 2) ? S_N : S_RZ;
            aI[p][kt] = cvt_half8_s(Wih + roff, s);  pin_frag(aI[p][kt]);
            aH[p][kt] = cvt_half8_s(Whh + roff, s);  pin_frag(aH[p][kt]);
        }

    // ---- bias seeds (scaled): r,z fold bih+bhh into x-GEMM; n splits ----
    const float* bi = bih + g * J3_;
    const float* bh = bhh + g * J3_;
    f32x4 s0 = (*(const f32x4*)(bi + jl)       + *(const f32x4*)(bh + jl))       * S_RZ;
    f32x4 s1 = (*(const f32x4*)(bi + 128 + jl) + *(const f32x4*)(bh + 128 + jl)) * S_RZ;
    f32x4 s2 = (*(const f32x4*)(bi + 256 + jl)) * S_N;
    f32x4 bhn_s = (*(const f32x4*)(bh + 256 + jl)) * S_N;
    pin_f32x4(s0); pin_f32x4(s1); pin_f32x4(s2); pin_f32x4(bhn_s);

    // ---- h = 0 init ----
    float hreg = 0.f;
    if (tid < HG_) h16[0][tid] = (_Float16)0.f;

    // x addressing: this lane's GEMM column = timestep lr of sequence b
    const _Float16* xcol = x16 + (size_t)b * T_ * IN_ + g * HG_;
    float*          oown = out + (size_t)b * T_ * IN_ + g * HG_ + jown;

    // ---- prologue: batch 0 (steps 0..15) burst into xmem[0] ----
    half8 bx[4];
    {
        const _Float16* px = xcol + (size_t)lr * IN_;
#pragma unroll
        for (int kt = 0; kt < 4; ++kt) bx[kt] = *(const half8*)(px + kt * 32 + hi * 8);
    }
    {
        f32x4 d0 = s0, d1 = s1, d2 = s2;
#pragma unroll
        for (int kt = 0; kt < 4; ++kt) {
            d0 = MFMA16(aI[0][kt], bx[kt], d0);
            d1 = MFMA16(aI[1][kt], bx[kt], d1);
            d2 = MFMA16(aI[2][kt], bx[kt], d2);
        }
        *(f32x4*)&xmem[0][lr][      w * 16 + hi * 4] = d0;
        *(f32x4*)&xmem[0][lr][128 + w * 16 + hi * 4] = d1;
        *(f32x4*)&xmem[0][lr][256 + w * 16 + hi * 4] = d2;
    }
    // load bx for batch 1 (steps 16..31)
    {
        int tn = 16 + lr; if (tn > T_ - 1) tn = T_ - 1;
        const _Float16* px = xcol + (size_t)tn * IN_;
#pragma unroll
        for (int kt = 0; kt < 4; ++kt) bx[kt] = *(const half8*)(px + kt * 32 + hi * 8);
    }
    // prefetch xa for step 0 (same-wave xmem data; uniform broadcast)
    f32x4 pxa0, pxa1, pxa2;
    pxa0 = *(const f32x4*)&xmem[0][0][      jl];
    pxa1 = *(const f32x4*)&xmem[0][0][128 + jl];
    pxa2 = *(const f32x4*)&xmem[0][0][256 + jl];
    // rolling x-batch accumulators (live across steps 0..3 of each batch)
    f32x4 d0, d1, d2;

    __syncthreads();   // once, outside the loop

#define REC_STEP(S)                                                                \
    do {                                                                           \
        const int pb = (S) & 1;                                                    \
        /* 1. h B-frags: uniform broadcast reads (one h vector, all cols) */       \
        const _Float16* hsrc = &h16[pb][0];                                        \
        const half8 bf0 = *(const half8*)(hsrc +  0 + hi * 8);                     \
        const half8 bf1 = *(const half8*)(hsrc + 32 + hi * 8);                     \
        const half8 bf2 = *(const half8*)(hsrc + 64 + hi * 8);                     \
        const half8 bf3 = *(const half8*)(hsrc + 96 + hi * 8);                     \
        /* 2. x-GEMM slice for next batch (kt = S, steps 0..3) */                  \
        if ((S) == 0) { d0 = s0; d1 = s1; d2 = s2; }                               \
        if ((S) < 4) {                                                             \
            d0 = MFMA16(aI[0][(S) & 3], bx[(S) & 3], d0);                          \
            d1 = MFMA16(aI[1][(S) & 3], bx[(S) & 3], d1);                          \
            d2 = MFMA16(aI[2][(S) & 3], bx[(S) & 3], d2);                          \
        }                                                                          \
        /* 3. h-MFMA: 3 chains; prefetched xa / S_N*bh_n ride C-in */              \
        f32x4 h0 = pxa0, h1 = pxa1, h2 = bhn_s;                                    \
        h0 = MFMA16(aH[0][0], bf0, h0);                                            \
        h1 = MFMA16(aH[1][0], bf0, h1);                                            \
        h2 = MFMA16(aH[2][0], bf0, h2);                                            \
        h0 = MFMA16(aH[0][1], bf1, h0);                                            \
        h1 = MFMA16(aH[1][1], bf1, h1);                                            \
        h2 = MFMA16(aH[2][1], bf1, h2);                                            \
        h0 = MFMA16(aH[0][2], bf2, h0);                                            \
        h1 = MFMA16(aH[1][2], bf2, h1);                                            \
        h2 = MFMA16(aH[2][2], bf2, h2);                                            \
        h0 = MFMA16(aH[0][3], bf3, h0);                                            \
        h1 = MFMA16(aH[1][3], bf3, h1);                                            \
        h2 = MFMA16(aH[2][3], bf3, h2);                                            \
        /* 4. finish next batch at S==3: write xmem[xb^1], reload bx */            \
        if ((S) == 3) {                                                            \
            *(f32x4*)&xmem[xb ^ 1][lr][      w * 16 + hi * 4] = d0;                \
            *(f32x4*)&xmem[xb ^ 1][lr][128 + w * 16 + hi * 4] = d1;                \
            *(f32x4*)&xmem[xb ^ 1][lr][256 + w * 16 + hi * 4] = d2;                \
            int tn = t0 + 32 + lr; if (tn > T_ - 1) tn = T_ - 1;                   \
            const _Float16* px = xcol + (size_t)tn * IN_;                          \
            bx[0] = *(const half8*)(px +  0 + hi * 8);                             \
            bx[1] = *(const half8*)(px + 32 + hi * 8);                             \
            bx[2] = *(const half8*)(px + 64 + hi * 8);                             \
            bx[3] = *(const half8*)(px + 96 + hi * 8);                             \
        }                                                                          \
        /* 5. prefetch xa for step S+1 (uniform broadcast) */                      \
        {                                                                          \
            const int nxb = ((S) == 15) ? (xb ^ 1) : xb;                           \
            const int nxc = ((S) + 1) & 15;                                        \
            pxa0 = *(const f32x4*)&xmem[nxb][nxc][      jl];                       \
            pxa1 = *(const f32x4*)&xmem[nxb][nxc][128 + jl];                       \
            pxa2 = *(const f32x4*)&xmem[nxb][nxc][256 + jl];                       \
        }                                                                          \
        /* 6. gates for the ONE owned j: 6 trans per wave */                       \
        const float ar = sel4(h0, rsel);                                           \
        const float az = sel4(h1, rsel);                                           \
        const float an = sel4(h2, rsel);                                           \
        const float xn = xn_cur;                                                   \
        const float rg = __builtin_amdgcn_rcpf(1.f + __builtin_amdgcn_exp2f(ar));  \
        const float zg = __builtin_amdgcn_rcpf(1.f + __builtin_amdgcn_exp2f(az));  \
        const float pre = xn + rg * an;                                            \
        const float th  = __builtin_fmaf(2.f,                                      \
            __builtin_amdgcn_rcpf(1.f + __builtin_amdgcn_exp2f(pre)), -1.f);       \
        const float hnew = __builtin_fmaf(zg, hreg - th, th);                      \
        hreg = hnew;                                                               \
        /* 7. write h (one writer per j: lr<4) + out store */                      \
        if (lr < 4) {                                                              \
            h16[pb ^ 1][jown] = (_Float16)hnew;                                    \
            oown[(size_t)(t0 + (S)) * IN_] = hnew;                                 \
        }                                                                          \
        barrier_lds_only();                                                        \
    } while (0)

    for (int t0 = 0; t0 < T_; t0 += 16) {
        const int xb = (t0 >> 4) & 1;
        // xn captured at step entry (pxa2 is overwritten by the prefetch)
        { float xn_cur = sel4(pxa2, rsel); REC_STEP(0);  }
        { float xn_cur = sel4(pxa2, rsel); REC_STEP(1);  }
        { float xn_cur = sel4(pxa2, rsel); REC_STEP(2);  }
        { float xn_cur = sel4(pxa2, rsel); REC_STEP(3);  }
        if (t0 + 4 < T_) {   // tail batch (t0=496) has only 4 steps
            { float xn_cur = sel4(pxa2, rsel); REC_STEP(4);  }
            { float xn_cur = sel4(pxa2, rsel); REC_STEP(5);  }
            { float xn_cur = sel4(pxa2, rsel); REC_STEP(6);  }
            { float xn_cur = sel4(pxa2, rsel); REC_STEP(7);  }
            { float xn_cur = sel4(pxa2, rsel); REC_STEP(8);  }
            { float xn_cur = sel4(pxa2, rsel); REC_STEP(9);  }
            { float xn_cur = sel4(pxa2, rsel); REC_STEP(10); }
            { float xn_cur = sel4(pxa2, rsel); REC_STEP(11); }
            { float xn_cur = sel4(pxa2, rsel); REC_STEP(12); }
            { float xn_cur = sel4(pxa2, rsel); REC_STEP(13); }
            { float xn_cur = sel4(pxa2, rsel); REC_STEP(14); }
            { float xn_cur = sel4(pxa2, rsel); REC_STEP(15); }
        }
    }
#undef REC_STEP
}

// ---------------------------------------------------------------------------
extern "C" void kernel_launch(void* const* d_in, const int* in_sizes, int n_in,
                              void* d_out, int out_size, void* d_ws, size_t ws_size,
                              hipStream_t stream) {
    (void)in_sizes; (void)n_in; (void)out_size; (void)ws_size;
    const float* x   = (const float*)d_in[0];
    const float* Wih = (const float*)d_in[1];
    const float* Whh = (const float*)d_in[2];
    const float* bih = (const float*)d_in[3];
    const float* bhh = (const float*)d_in[4];
    float* out = (float*)d_out;

    _Float16* x16 = (_Float16*)d_ws;    // 65.5 MB

    cvt_x<<<4096, 256, 0, stream>>>(x, x16);
    gru_fused<<<512, 512, 0, stream>>>(Wih, Whh, bih, bhh, x16, out);
}

// Round 18
// 259.776 us; speedup vs baseline: 1.9364x; 1.9364x over previous
//
#include <hip/hip_runtime.h>
#include <math.h>

#define B_   64
#define T_   500
#define IN_  1024
#define G_   8
#define HG_  128
#define J3_  384   // 3*HG

typedef _Float16 half8 __attribute__((ext_vector_type(8)));
typedef _Float16 half4 __attribute__((ext_vector_type(4)));
typedef float    f32x4 __attribute__((ext_vector_type(4)));

// sigmoid(a) = rcp(1 + exp2(S_RZ*a)); tanh(p) = 2*rcp(1+exp2(S_N*p))-1.
// Scales folded into the f16 weights and bias seeds (no muls in gates).
#define S_RZ (-1.44269504f)
#define S_N  (-2.88539008f)

static __device__ __forceinline__ half8 cvt_half8_s(const float* p, float s) {
    const float4 a = *(const float4*)p;
    const float4 b = *(const float4*)(p + 4);
    half8 h;
    h[0]=(_Float16)(a.x*s); h[1]=(_Float16)(a.y*s); h[2]=(_Float16)(a.z*s); h[3]=(_Float16)(a.w*s);
    h[4]=(_Float16)(b.x*s); h[5]=(_Float16)(b.y*s); h[6]=(_Float16)(b.z*s); h[7]=(_Float16)(b.w*s);
    return h;
}

// opaque reg-to-reg barrier: prevents rematerialization of loop-invariant state
static __device__ __forceinline__ void pin_frag(half8& h) {
    f32x4 t = __builtin_bit_cast(f32x4, h);
    float a = t[0], b = t[1], c = t[2], d = t[3];
    asm volatile("" : "+v"(a), "+v"(b), "+v"(c), "+v"(d));
    t[0] = a; t[1] = b; t[2] = c; t[3] = d;
    h = __builtin_bit_cast(half8, t);
}
static __device__ __forceinline__ void pin_f32x4(f32x4& v) {
    float a = v[0], b = v[1], c = v[2], d = v[3];
    asm volatile("" : "+v"(a), "+v"(b), "+v"(c), "+v"(d));
    v[0] = a; v[1] = b; v[2] = c; v[3] = d;
}

// LDS-only barrier: orders ds ops across the workgroup WITHOUT draining vmcnt.
static __device__ __forceinline__ void barrier_lds_only() {
    asm volatile("s_waitcnt lgkmcnt(0)\n\ts_barrier" ::: "memory");
}

// per-lane select of one element from an f32x4 (constant indices only; the
// two rsel-masks are loop-invariant and hoisted)
static __device__ __forceinline__ float sel4(f32x4 v, int rsel) {
    const float t0 = (rsel & 1) ? v[1] : v[0];
    const float t1 = (rsel & 1) ? v[3] : v[2];
    return (rsel & 2) ? t1 : t0;
}

#define MFMA16(A,Bv,C) __builtin_amdgcn_mfma_f32_16x16x32_f16((A),(Bv),(C),0,0,0)

// ---------------------------------------------------------------------------
// Kernel 0: cast x (fp32) -> x16 (f16), one-shot, memory-bound (~30 us).
// ---------------------------------------------------------------------------
__global__ __launch_bounds__(256)
void cvt_x(const float* __restrict__ x, _Float16* __restrict__ x16)
{
    const size_t n4 = (size_t)B_ * T_ * IN_ / 4;
    const size_t stride = (size_t)gridDim.x * 256;
    for (size_t i = (size_t)blockIdx.x * 256 + threadIdx.x; i < n4; i += stride) {
        const float4 v = ((const float4*)x)[i];
        half4 h;
        h[0] = (_Float16)v.x; h[1] = (_Float16)v.y;
        h[2] = (_Float16)v.z; h[3] = (_Float16)v.w;
        ((half4*)x16)[i] = h;
    }
}

// ---------------------------------------------------------------------------
// Kernel 1 (structure G7 — REVERT to the measured-best 260us configuration):
// 256 blocks x 512 thr (8 waves), 2 real seqs/block.
// Round-17 falsified the 2-blocks/CU line for good: forcing the 128-reg cap
// (waves_per_eu(4,4)) spilled the persistent state (VGPR 96->64, FETCH
// 33MB->758MB scratch traffic) and regressed 267->521us. The fused kernel's
// resident state (~150 regs) cannot fit 128; dropping aI to fit (r13) loses
// more than interleaving recovers. G7's step budget: MFMA-issue 430cy
// (floor at the 8x col-duplication full-chip activity requires), VALU 392cy
// (4x-dedup'd gates, folded scales, C-in biases), ~300cy barrier skew at
// 1 block/CU. 500 serial steps x ~1120cy ~= 267us.
// ---------------------------------------------------------------------------
__global__ __launch_bounds__(512, 1)
void gru_fused(const float* __restrict__ Wih, const float* __restrict__ Whh,
               const float* __restrict__ bih, const float* __restrict__ bhh,
               const _Float16* __restrict__ x16, float* __restrict__ out)
{
    const int tid  = threadIdx.x;
    const int lane = tid & 63;
    const int w    = tid >> 6;        // wave 0..7 == j-tile
    const int lr   = lane & 15;       // MFMA col
    const int hi   = lane >> 4;       // 0..3
    const int blk  = blockIdx.x;      // 0..255
    const int g    = blk & 7;         // == XCD
    const int bp   = blk >> 3;        // 0..31
    const int sq   = lr & 1;          // seq parity
    const int rsel = (lr >> 1) & 3;   // the ONE r this lane owns
    const int jl   = w * 16 + hi * 4;
    const int jown = jl + rsel;       // owned j
    const int bown = bp * 2 + sq;     // owned sequence

    __shared__ _Float16 h16[2][2][HG_];      // 1 KB: [buf][seq][j]
    __shared__ float    xmem[2][16][392];    // 49 KB: [xbuf][col=ts*2+seq][gate*128+j]

    // ---- persistent pinned fragments, gate scales folded in ----
    half8 aI[3][4], aH[3][4];
#pragma unroll
    for (int p = 0; p < 3; ++p)
#pragma unroll
        for (int kt = 0; kt < 4; ++kt) {
            const size_t roff = (size_t)(g * J3_ + p * 128 + w * 16 + lr) * HG_
                              + kt * 32 + hi * 8;
            const float s = (p == 2) ? S_N : S_RZ;
            aI[p][kt] = cvt_half8_s(Wih + roff, s);  pin_frag(aI[p][kt]);
            aH[p][kt] = cvt_half8_s(Whh + roff, s);  pin_frag(aH[p][kt]);
        }

    // ---- bias seeds (scaled): r,z fold bih+bhh into x-GEMM; n splits ----
    const float* bi = bih + g * J3_;
    const float* bh = bhh + g * J3_;
    f32x4 s0 = (*(const f32x4*)(bi + jl)       + *(const f32x4*)(bh + jl))       * S_RZ;
    f32x4 s1 = (*(const f32x4*)(bi + 128 + jl) + *(const f32x4*)(bh + 128 + jl)) * S_RZ;
    f32x4 s2 = (*(const f32x4*)(bi + 256 + jl)) * S_N;
    f32x4 bhn_s = (*(const f32x4*)(bh + 256 + jl)) * S_N;
    pin_f32x4(s0); pin_f32x4(s1); pin_f32x4(s2); pin_f32x4(bhn_s);

    // ---- h = 0 init ----
    float hreg = 0.f;
    if (tid < 256) h16[0][tid >> 7][tid & 127] = (_Float16)0.f;

    // x addressing: this lane's GEMM column = (ts = lr>>1, seq = lr&1)
    const _Float16* xcol = x16 + (size_t)(bp * 2 + (lr & 1)) * T_ * IN_ + g * HG_;
    float*          oown = out + (size_t)bown * T_ * IN_ + g * HG_ + jown;

    // ---- prologue: batch 0 (steps 0..7) burst into xmem[0] ----
    half8 bx[4];
    {
        const _Float16* px = xcol + (size_t)(lr >> 1) * IN_;
#pragma unroll
        for (int kt = 0; kt < 4; ++kt) bx[kt] = *(const half8*)(px + kt * 32 + hi * 8);
    }
    {
        f32x4 d0 = s0, d1 = s1, d2 = s2;
#pragma unroll
        for (int kt = 0; kt < 4; ++kt) {
            d0 = MFMA16(aI[0][kt], bx[kt], d0);
            d1 = MFMA16(aI[1][kt], bx[kt], d1);
            d2 = MFMA16(aI[2][kt], bx[kt], d2);
        }
        *(f32x4*)&xmem[0][lr][      w * 16 + hi * 4] = d0;
        *(f32x4*)&xmem[0][lr][128 + w * 16 + hi * 4] = d1;
        *(f32x4*)&xmem[0][lr][256 + w * 16 + hi * 4] = d2;
    }
    // load bx for batch 1 (steps 8..15)
    {
        int tn = 8 + (lr >> 1); if (tn > T_ - 1) tn = T_ - 1;
        const _Float16* px = xcol + (size_t)tn * IN_;
#pragma unroll
        for (int kt = 0; kt < 4; ++kt) bx[kt] = *(const half8*)(px + kt * 32 + hi * 8);
    }
    // prefetch xa for step 0 (same-wave xmem data; no barrier needed)
    f32x4 pxa0, pxa1, pxa2;
    {
        const int xc = sq;
        pxa0 = *(const f32x4*)&xmem[0][xc][      jl];
        pxa1 = *(const f32x4*)&xmem[0][xc][128 + jl];
        pxa2 = *(const f32x4*)&xmem[0][xc][256 + jl];
    }
    // rolling x-batch accumulators (live across steps 0..3)
    f32x4 d0, d1, d2;

    __syncthreads();   // once, outside the loop

#define REC_STEP(S)                                                                \
    do {                                                                           \
        const int pb = (S) & 1;                                                    \
        /* 1. h B-frags: broadcast reads */                                        \
        const _Float16* hsrc = &h16[pb][sq][0];                                    \
        const half8 bf0 = *(const half8*)(hsrc +  0 + hi * 8);                     \
        const half8 bf1 = *(const half8*)(hsrc + 32 + hi * 8);                     \
        const half8 bf2 = *(const half8*)(hsrc + 64 + hi * 8);                     \
        const half8 bf3 = *(const half8*)(hsrc + 96 + hi * 8);                     \
        /* 2. x-GEMM slice for next batch (kt = S, steps 0..3) */                  \
        if ((S) == 0) { d0 = s0; d1 = s1; d2 = s2; }                               \
        if ((S) < 4) {                                                             \
            d0 = MFMA16(aI[0][(S) & 3], bx[(S) & 3], d0);                          \
            d1 = MFMA16(aI[1][(S) & 3], bx[(S) & 3], d1);                          \
            d2 = MFMA16(aI[2][(S) & 3], bx[(S) & 3], d2);                          \
        }                                                                          \
        /* 3. h-MFMA: 3 chains; prefetched xa / S_N*bh_n ride C-in */              \
        f32x4 h0 = pxa0, h1 = pxa1, h2 = bhn_s;                                    \
        h0 = MFMA16(aH[0][0], bf0, h0);                                            \
        h1 = MFMA16(aH[1][0], bf0, h1);                                            \
        h2 = MFMA16(aH[2][0], bf0, h2);                                            \
        h0 = MFMA16(aH[0][1], bf1, h0);                                            \
        h1 = MFMA16(aH[1][1], bf1, h1);                                            \
        h2 = MFMA16(aH[2][1], bf1, h2);                                            \
        h0 = MFMA16(aH[0][2], bf2, h0);                                            \
        h1 = MFMA16(aH[1][2], bf2, h1);                                            \
        h2 = MFMA16(aH[2][2], bf2, h2);                                            \
        h0 = MFMA16(aH[0][3], bf3, h0);                                            \
        h1 = MFMA16(aH[1][3], bf3, h1);                                            \
        h2 = MFMA16(aH[2][3], bf3, h2);                                            \
        /* 4. finish next batch at S==3: write xmem[xb^1], reload bx */            \
        if ((S) == 3) {                                                            \
            *(f32x4*)&xmem[xb ^ 1][lr][      w * 16 + hi * 4] = d0;                \
            *(f32x4*)&xmem[xb ^ 1][lr][128 + w * 16 + hi * 4] = d1;                \
            *(f32x4*)&xmem[xb ^ 1][lr][256 + w * 16 + hi * 4] = d2;                \
            int tn = t0 + 16 + (lr >> 1); if (tn > T_ - 1) tn = T_ - 1;            \
            const _Float16* px = xcol + (size_t)tn * IN_;                          \
            bx[0] = *(const half8*)(px +  0 + hi * 8);                             \
            bx[1] = *(const half8*)(px + 32 + hi * 8);                             \
            bx[2] = *(const half8*)(px + 64 + hi * 8);                             \
            bx[3] = *(const half8*)(px + 96 + hi * 8);                             \
        }                                                                          \
        /* 5. prefetch xa for step S+1 (same-wave xmem data) */                    \
        {                                                                          \
            const int nxb = ((S) == 7) ? (xb ^ 1) : xb;                            \
            const int nxc = (((S) + 1) & 7) * 2 + sq;                              \
            pxa0 = *(const f32x4*)&xmem[nxb][nxc][      jl];                       \
            pxa1 = *(const f32x4*)&xmem[nxb][nxc][128 + jl];                       \
            pxa2 = *(const f32x4*)&xmem[nxb][nxc][256 + jl];                       \
        }                                                                          \
        /* 6. gates for the ONE owned (seq, j): 6 trans per wave */                \
        const float ar = sel4(h0, rsel);                                           \
        const float az = sel4(h1, rsel);                                           \
        const float an = sel4(h2, rsel);                                           \
        const float xn = xn_cur;                                                   \
        const float rg = __builtin_amdgcn_rcpf(1.f + __builtin_amdgcn_exp2f(ar));  \
        const float zg = __builtin_amdgcn_rcpf(1.f + __builtin_amdgcn_exp2f(az));  \
        const float pre = xn + rg * an;                                            \
        const float th  = __builtin_fmaf(2.f,                                      \
            __builtin_amdgcn_rcpf(1.f + __builtin_amdgcn_exp2f(pre)), -1.f);       \
        const float hnew = __builtin_fmaf(zg, hreg - th, th);                      \
        hreg = hnew;                                                               \
        /* 7. write h (one writer per value) + out store */                        \
        if (lr < 8) {                                                              \
            h16[pb ^ 1][sq][jown] = (_Float16)hnew;                                \
            oown[(size_t)(t0 + (S)) * IN_] = hnew;                                 \
        }                                                                          \
        barrier_lds_only();                                                        \
    } while (0)

    for (int t0 = 0; t0 < T_; t0 += 8) {
        const int xb = (t0 >> 3) & 1;
        // xn for the current step captured BEFORE pxa2 is overwritten by the
        // prefetch; sel4 it at step entry.
        { float xn_cur = sel4(pxa2, rsel); REC_STEP(0); }
        { float xn_cur = sel4(pxa2, rsel); REC_STEP(1); }
        { float xn_cur = sel4(pxa2, rsel); REC_STEP(2); }
        { float xn_cur = sel4(pxa2, rsel); REC_STEP(3); }
        if (t0 + 4 < T_) {
            { float xn_cur = sel4(pxa2, rsel); REC_STEP(4); }
            { float xn_cur = sel4(pxa2, rsel); REC_STEP(5); }
            { float xn_cur = sel4(pxa2, rsel); REC_STEP(6); }
            { float xn_cur = sel4(pxa2, rsel); REC_STEP(7); }
        }
    }
#undef REC_STEP
}

// ---------------------------------------------------------------------------
extern "C" void kernel_launch(void* const* d_in, const int* in_sizes, int n_in,
                              void* d_out, int out_size, void* d_ws, size_t ws_size,
                              hipStream_t stream) {
    (void)in_sizes; (void)n_in; (void)out_size; (void)ws_size;
    const float* x   = (const float*)d_in[0];
    const float* Wih = (const float*)d_in[1];
    const float* Whh = (const float*)d_in[2];
    const float* bih = (const float*)d_in[3];
    const float* bhh = (const float*)d_in[4];
    float* out = (float*)d_out;

    _Float16* x16 = (_Float16*)d_ws;    // 65.5 MB

    cvt_x<<<4096, 256, 0, stream>>>(x, x16);
    gru_fused<<<256, 512, 0, stream>>>(Wih, Whh, bih, bhh, x16, out);
}